// Round 1
// baseline (514.595 us; speedup 1.0000x reference)
//
#include <hip/hip_runtime.h>

// Problem constants (from reference)
#define TT 2048
#define BB 4096
#define OUT_STRIDE_T (BB * 4)                  // floats per timestep slab [B,4]
#define OUT_LSTM ((size_t)TT * (size_t)BB * 4) // floats per LSTM output tensor

static __device__ __forceinline__ float fast_exp2(float a) { return __builtin_amdgcn_exp2f(a); }
static __device__ __forceinline__ float fast_rcp(float a)  { return __builtin_amdgcn_rcpf(a); }

// Lane layout: 16 lanes per batch element b.
//   role = gtid & 15:  j = role&3 (hidden unit), isL2 = (role>>2)&1 (layer),
//   lstm = role>>3 (0 = dropout-weights LSTM, 1 = no-dropout LSTM).
// Layer 2 runs one timestep behind layer 1 (pipelined via in-wave bpermute),
// so every lane executes the identical instruction stream each iteration.
__global__ __launch_bounds__(256, 1) void lstm2x2_kernel(
    const float* __restrict__ x,
    const float* __restrict__ wihd, const float* __restrict__ whhd,
    const float* __restrict__ bihd, const float* __restrict__ bhhd,
    const float* __restrict__ wihn, const float* __restrict__ whhn,
    const float* __restrict__ bihn, const float* __restrict__ bhhn,
    float* __restrict__ out)
{
    const int gtid = blockIdx.x * blockDim.x + threadIdx.x;
    const int b    = gtid >> 4;
    const int role = gtid & 15;
    const int j    = role & 3;
    const int isL2 = (role >> 2) & 1;
    const int lstm = (role >> 3) & 1;
    const int lane = threadIdx.x & 63;

    const float* wih = lstm ? wihn : wihd;
    const float* whh = lstm ? whhn : whhd;
    const float* bih = lstm ? bihn : bihd;
    const float* bhh = lstm ? bhhn : bhhd;

    constexpr float L2E = 1.44269504088896340736f;

    // Per-lane weights in VGPRs, prescaled so activations need only exp2+rcp:
    //   i,f,o rows: * -log2(e)   -> p = exp2(acc) = e^{-z},  sigma = rcp(1+p)
    //   g row:      * -2*log2(e) -> p = e^{-2z},  tanh = (1-p)*rcp(1+p)
    // W_hh columns (and W_ih columns for layer 2) are XOR-j permuted so the
    // shfl_xor gather order matches the weight order with zero fixup ops.
    float WA[4][4], WB[4][4], BS[4];
#pragma unroll
    for (int g = 0; g < 4; ++g) {
        const float sc = (g == 2) ? (-2.0f * L2E) : (-L2E);
        const int row = isL2 * 16 + g * 4 + j;   // torch gate order i,f,g,o
#pragma unroll
        for (int m = 0; m < 4; ++m) {
            const int colA = isL2 ? (j ^ m) : m; // layer1 input = x (natural order)
            WA[g][m] = wih[row * 4 + colA] * sc;
            WB[g][m] = whh[row * 4 + (j ^ m)] * sc;
        }
        BS[g] = (bih[row] + bhh[row]) * sc;
    }

    // Cross-layer fetch source lanes: layer-2 lane reads h1 from the 4-lane
    // group 4 lanes to its left, in XOR-j order. (&63 keeps it in-wave; the
    // wrapped values for layer-1 lanes are fetched but never used.)
    const int gb4 = lane & ~3;
    const int cs0 = ((gb4 - 4) & 63) | (j ^ 0);
    const int cs1 = ((gb4 - 4) & 63) | (j ^ 1);
    const int cs2 = ((gb4 - 4) & 63) | (j ^ 2);
    const int cs3 = ((gb4 - 4) & 63) | (j ^ 3);

    // x prefetch ring, depth 8 (~8 steps * ~170cy covers ~900cy HBM latency).
    // All lanes load (L2 lanes duplicate L1's address -> coalesces, no extra
    // HBM lines). Indices are static after the unroll-by-8 below.
    const float4* xb = reinterpret_cast<const float4*>(x) + b;
    float4 xr[8];
#pragma unroll
    for (int i = 0; i < 8; ++i) xr[i] = xb[(size_t)i * BB];

    float* outp = out + (size_t)lstm * OUT_LSTM + (size_t)b * 4 + j;

    float h = 0.0f, c = 0.0f;

    // Iteration s: layer-1 lanes compute t=s, layer-2 lanes compute t=s-1.
    // 2049 useful iterations padded to 2056 (= 8*257) for the ring unroll;
    // store guard (s<=TT) makes the pad iterations harmless.
#pragma unroll 8
    for (int s = 0; s < 2056; ++s) {
        const int k = s & 7;

        // Gathers on previous-iteration h registers.
        const float o1 = __shfl_xor(h, 1);          // own-layer h, xor order
        const float o2 = __shfl_xor(h, 2);
        const float o3 = __shfl_xor(h, 3);
        const float i0 = __shfl(h, cs0);            // layer-1 h for layer-2 input
        const float i1 = __shfl(h, cs1);
        const float i2 = __shfl(h, cs2);
        const float i3 = __shfl(h, cs3);

        const float a0 = isL2 ? i0 : xr[k].x;
        const float a1 = isL2 ? i1 : xr[k].y;
        const float a2 = isL2 ? i2 : xr[k].z;
        const float a3 = isL2 ? i3 : xr[k].w;

        // Refill ring slot for t = s+8 (clamped; tail loads re-read x[T-1]).
        int tld = s + 8;
        if (tld > TT - 1) tld = TT - 1;
        xr[k] = xb[(size_t)tld * BB];

        // Gate pre-activations (already scaled): 8 FMA per gate, 4-way ILP.
        float acc0 = BS[0], acc1 = BS[1], acc2 = BS[2], acc3 = BS[3];
        acc0 = fmaf(WA[0][0], a0, acc0); acc0 = fmaf(WA[0][1], a1, acc0);
        acc0 = fmaf(WA[0][2], a2, acc0); acc0 = fmaf(WA[0][3], a3, acc0);
        acc0 = fmaf(WB[0][0], h,  acc0); acc0 = fmaf(WB[0][1], o1, acc0);
        acc0 = fmaf(WB[0][2], o2, acc0); acc0 = fmaf(WB[0][3], o3, acc0);

        acc1 = fmaf(WA[1][0], a0, acc1); acc1 = fmaf(WA[1][1], a1, acc1);
        acc1 = fmaf(WA[1][2], a2, acc1); acc1 = fmaf(WA[1][3], a3, acc1);
        acc1 = fmaf(WB[1][0], h,  acc1); acc1 = fmaf(WB[1][1], o1, acc1);
        acc1 = fmaf(WB[1][2], o2, acc1); acc1 = fmaf(WB[1][3], o3, acc1);

        acc2 = fmaf(WA[2][0], a0, acc2); acc2 = fmaf(WA[2][1], a1, acc2);
        acc2 = fmaf(WA[2][2], a2, acc2); acc2 = fmaf(WA[2][3], a3, acc2);
        acc2 = fmaf(WB[2][0], h,  acc2); acc2 = fmaf(WB[2][1], o1, acc2);
        acc2 = fmaf(WB[2][2], o2, acc2); acc2 = fmaf(WB[2][3], o3, acc2);

        acc3 = fmaf(WA[3][0], a0, acc3); acc3 = fmaf(WA[3][1], a1, acc3);
        acc3 = fmaf(WA[3][2], a2, acc3); acc3 = fmaf(WA[3][3], a3, acc3);
        acc3 = fmaf(WB[3][0], h,  acc3); acc3 = fmaf(WB[3][1], o1, acc3);
        acc3 = fmaf(WB[3][2], o2, acc3); acc3 = fmaf(WB[3][3], o3, acc3);

        // Activations: 5 exp2 + 5 rcp per step.
        const float p0 = fast_exp2(acc0);   // e^{-z_i}
        const float p1 = fast_exp2(acc1);   // e^{-z_f}
        const float p2 = fast_exp2(acc2);   // e^{-2 z_g}
        const float p3 = fast_exp2(acc3);   // e^{-z_o}
        const float iv = fast_rcp(1.0f + p0);
        const float fv = fast_rcp(1.0f + p1);
        const float gv = (1.0f - p2) * fast_rcp(1.0f + p2);
        const float ov = fast_rcp(1.0f + p3);

        float cn = fmaf(fv, c, iv * gv);
        // tanh(c) via |c| form: q in (0,1] -> no inf/NaN for any c.
        const float q  = fast_exp2(-2.0f * L2E * fabsf(cn));
        float th = (1.0f - q) * fast_rcp(1.0f + q);
        th = copysignf(th, cn);
        float hn = ov * th;

        // s==0: layer-2 lanes ran on garbage input (pipeline not filled yet);
        // keep their state at zero. Folds to a select in unrolled body 0 only.
        if (s == 0 && isL2) { cn = 0.0f; hn = 0.0f; }

        c = cn;
        h = hn;

        // Layer-2 lanes own the final outputs: at iteration s they computed
        // timestep t = s-1.
        if (s >= 1 && s <= TT) {
            if (isL2) {
                outp[(size_t)(s - 1) * OUT_STRIDE_T] = hn;
            }
        }
    }
}

extern "C" void kernel_launch(void* const* d_in, const int* in_sizes, int n_in,
                              void* d_out, int out_size, void* d_ws, size_t ws_size,
                              hipStream_t stream)
{
    const float* x    = (const float*)d_in[0];
    const float* wihd = (const float*)d_in[1];
    const float* whhd = (const float*)d_in[2];
    const float* bihd = (const float*)d_in[3];
    const float* bhhd = (const float*)d_in[4];
    const float* wihn = (const float*)d_in[5];
    const float* whhn = (const float*)d_in[6];
    const float* bihn = (const float*)d_in[7];
    const float* bhhn = (const float*)d_in[8];
    float* out = (float*)d_out;

    // 4096 batch elems * 16 lanes = 65536 threads = 256 blocks of 256.
    lstm2x2_kernel<<<dim3(256), dim3(256), 0, stream>>>(
        x, wihd, whhd, bihd, bhhd, wihn, whhn, bihn, bhhn, out);
}

// Round 2
// 341.601 us; speedup vs baseline: 1.5064x; 1.5064x over previous
//
#include <hip/hip_runtime.h>

// Problem constants (from reference)
#define TT 2048
#define BB 4096
#define OUT_STRIDE_T (BB * 4)                  // floats per timestep slab [B,4]
#define OUT_LSTM ((size_t)TT * (size_t)BB * 4) // floats per LSTM output tensor

typedef float f2 __attribute__((ext_vector_type(2)));

static __device__ __forceinline__ float fast_exp2(float a) { return __builtin_amdgcn_exp2f(a); }
static __device__ __forceinline__ float fast_rcp(float a)  { return __builtin_amdgcn_rcpf(a); }

// DPP cross-lane move (pure VALU — no DS pipe, no lgkmcnt stall).
// quad_perm xor1=0xB1, xor2=0x4E, xor3=0x1B; row_shr:4 = 0x114.
template<int CTRL>
static __device__ __forceinline__ float dpp_f32(float x) {
    int xi = __builtin_bit_cast(int, x);
    int r  = __builtin_amdgcn_update_dpp(0, xi, CTRL, 0xF, 0xF, true);
    return __builtin_bit_cast(float, r);
}

// Packed dual-FP32 FMA (full rate on CDNA3+): d = a*b + c per 32-bit half.
static __device__ __forceinline__ f2 pk_fma(f2 a, f2 b, f2 c) {
    f2 d;
    asm("v_pk_fma_f32 %0, %1, %2, %3" : "=v"(d) : "v"(a), "v"(b), "v"(c));
    return d;
}

// Lane layout: 16 lanes per batch element b.
//   role = gtid & 15:  j = role&3 (hidden unit), isL2 = (role>>2)&1 (layer),
//   lstm = role>>3 (0 = dropout-weights LSTM, 1 = no-dropout LSTM).
// Layer 2 runs one timestep skewed behind layer 1 (pipelined via DPP row_shr:4),
// so every lane executes the identical instruction stream each iteration.
__global__ __launch_bounds__(256, 1) void lstm2x2_kernel(
    const float* __restrict__ x,
    const float* __restrict__ wihd, const float* __restrict__ whhd,
    const float* __restrict__ bihd, const float* __restrict__ bhhd,
    const float* __restrict__ wihn, const float* __restrict__ whhn,
    const float* __restrict__ bihn, const float* __restrict__ bhhn,
    float* __restrict__ out)
{
    const int gtid = blockIdx.x * blockDim.x + threadIdx.x;
    const int b    = gtid >> 4;
    const int role = gtid & 15;
    const int j    = role & 3;
    const int isL2 = (role >> 2) & 1;
    const int lstm = (role >> 3) & 1;

    const float* wih = lstm ? wihn : wihd;
    const float* whh = lstm ? whhn : whhd;
    const float* bih = lstm ? bihn : bihd;
    const float* bhh = lstm ? bhhn : bhhd;

    constexpr float L2E = 1.44269504088896340736f;

    // Per-lane packed weights, prescaled so activations need only exp2+rcp:
    //   i,f,o rows: * -log2(e)   -> p = exp2(z') = e^{-z},  sigma = rcp(1+p)
    //   g row:      * -2*log2(e) -> p = e^{-2z},  tanh = (1-p)*rcp(1+p)
    // Pairing is over the input index m: pair {m=0,1} and {m=2,3}, so the
    // A-operand pairs come straight from the float4 x load / DPP results.
    // W_hh columns (and W_ih columns for layer 2) are XOR-j permuted to match
    // the quad_perm gather order with zero fixup ops.
    f2 WA01[4], WA23[4], WB01[4], WB23[4], BZ[4];
#pragma unroll
    for (int g = 0; g < 4; ++g) {
        const float sc = (g == 2) ? (-2.0f * L2E) : (-L2E);
        const int row = isL2 * 16 + g * 4 + j;   // torch gate order i,f,g,o
        float wa[4], wb[4];
#pragma unroll
        for (int m = 0; m < 4; ++m) {
            const int colA = isL2 ? (j ^ m) : m; // layer1 input = x (natural)
            wa[m] = wih[row * 4 + colA] * sc;
            wb[m] = whh[row * 4 + (j ^ m)] * sc;
        }
        WA01[g] = f2{wa[0], wa[1]};
        WA23[g] = f2{wa[2], wa[3]};
        WB01[g] = f2{wb[0], wb[1]};
        WB23[g] = f2{wb[2], wb[3]};
        BZ[g]   = f2{(bih[row] + bhh[row]) * sc, 0.0f};
    }

    // x prefetch ring, depth 8 (~8 steps covers HBM latency). All lanes load
    // (L2 lanes duplicate L1's address -> coalesces, no extra HBM lines).
    const float4* xb = reinterpret_cast<const float4*>(x) + b;
    float4 xr[8];
#pragma unroll
    for (int i = 0; i < 8; ++i) xr[i] = xb[(size_t)i * BB];

    float* outp = out + (size_t)lstm * OUT_LSTM + (size_t)b * 4 + j;

    float h = 0.0f, c = 0.0f;

    // One LSTM step for this lane's cell. Uses/updates h (via return) and c.
    auto do_step = [&](float4 xk) -> float {
        // Cross-lane gathers on previous-step h — all DPP (VALU).
        const float o1 = dpp_f32<0xB1>(h);   // own-quad h[j^1]
        const float o2 = dpp_f32<0x4E>(h);   // own-quad h[j^2]
        const float o3 = dpp_f32<0x1B>(h);   // own-quad h[j^3]
        const float i0 = dpp_f32<0x114>(h);  // layer-1 h[j^0] (for L2 lanes)
        const float i1 = dpp_f32<0x114>(o1); // layer-1 h[j^1]
        const float i2 = dpp_f32<0x114>(o2); // layer-1 h[j^2]
        const float i3 = dpp_f32<0x114>(o3); // layer-1 h[j^3]

        f2 A01, A23, H01, H23;
        A01.x = isL2 ? i0 : xk.x;
        A01.y = isL2 ? i1 : xk.y;
        A23.x = isL2 ? i2 : xk.z;
        A23.y = isL2 ? i3 : xk.w;
        H01.x = h;  H01.y = o1;
        H23.x = o2; H23.y = o3;

        // Gate pre-activations: 4 pk_fma deep per gate (bias preloaded in
        // the lo half of BZ), then one horizontal add.
        f2 t0 = pk_fma(WA01[0], A01, BZ[0]);
        t0 = pk_fma(WA23[0], A23, t0);
        t0 = pk_fma(WB01[0], H01, t0);
        t0 = pk_fma(WB23[0], H23, t0);

        f2 t1 = pk_fma(WA01[1], A01, BZ[1]);
        t1 = pk_fma(WA23[1], A23, t1);
        t1 = pk_fma(WB01[1], H01, t1);
        t1 = pk_fma(WB23[1], H23, t1);

        f2 t2 = pk_fma(WA01[2], A01, BZ[2]);
        t2 = pk_fma(WA23[2], A23, t2);
        t2 = pk_fma(WB01[2], H01, t2);
        t2 = pk_fma(WB23[2], H23, t2);

        f2 t3 = pk_fma(WA01[3], A01, BZ[3]);
        t3 = pk_fma(WA23[3], A23, t3);
        t3 = pk_fma(WB01[3], H01, t3);
        t3 = pk_fma(WB23[3], H23, t3);

        const float z0 = t0.x + t0.y;
        const float z1 = t1.x + t1.y;
        const float z2 = t2.x + t2.y;
        const float z3 = t3.x + t3.y;

        // Activations: 5 exp2 + 5 rcp per step.
        const float p0 = fast_exp2(z0);      // e^{-z_i}
        const float p1 = fast_exp2(z1);      // e^{-z_f}
        const float p2 = fast_exp2(z2);      // e^{-2 z_g}
        const float p3 = fast_exp2(z3);      // e^{-z_o}
        const float iv = fast_rcp(1.0f + p0);
        const float fv = fast_rcp(1.0f + p1);
        const float gv = (1.0f - p2) * fast_rcp(1.0f + p2);
        const float ov = fast_rcp(1.0f + p3);

        const float cn = fmaf(fv, c, iv * gv);
        // tanh(c) via |c| form: q in (0,1] -> no inf/NaN for any c.
        const float q  = fast_exp2(-2.0f * L2E * fabsf(cn));
        float th = (1.0f - q) * fast_rcp(1.0f + q);
        th = copysignf(th, cn);
        c = cn;
        return ov * th;
    };

    // Peel s=0: layer-2 lanes ran on a not-yet-filled pipeline; zero them.
    {
        float hn = do_step(xr[0]);
        xr[0] = xb[(size_t)8 * BB];
        if (isL2) { hn = 0.0f; c = 0.0f; }
        h = hn;
    }

    // Main loop: iteration s computes t=s on layer-1 lanes, t=s-1 on layer-2
    // lanes. Trip count 2048 = 8*256 -> ring index k=s&7 is static per
    // unrolled body; store is guard-free.
#pragma unroll 8
    for (int s = 1; s <= TT; ++s) {
        const int k = s & 7;
        float hn = do_step(xr[k]);
        int tld = s + 8; if (tld > TT - 1) tld = TT - 1;
        xr[k] = xb[(size_t)tld * BB];
        h = hn;
        if (isL2) outp[(size_t)(s - 1) * OUT_STRIDE_T] = hn;
    }
}

extern "C" void kernel_launch(void* const* d_in, const int* in_sizes, int n_in,
                              void* d_out, int out_size, void* d_ws, size_t ws_size,
                              hipStream_t stream)
{
    const float* x    = (const float*)d_in[0];
    const float* wihd = (const float*)d_in[1];
    const float* whhd = (const float*)d_in[2];
    const float* bihd = (const float*)d_in[3];
    const float* bhhd = (const float*)d_in[4];
    const float* wihn = (const float*)d_in[5];
    const float* whhn = (const float*)d_in[6];
    const float* bihn = (const float*)d_in[7];
    const float* bhhn = (const float*)d_in[8];
    float* out = (float*)d_out;

    // 4096 batch elems * 16 lanes = 65536 threads = 256 blocks of 256.
    lstm2x2_kernel<<<dim3(256), dim3(256), 0, stream>>>(
        x, wihd, whhd, bihd, bhhd, wihn, whhn, bihn, bhhn, out);
}